// Round 6
// baseline (240.411 us; speedup 1.0000x reference)
//
#include <hip/hip_runtime.h>

#define BSZ 32
#define SLEN 2048
#define NVAL 256
#define CHUNK 32                 // positions per k_main block
#define NCHUNK (SLEN / CHUNK)    // 64

// ---------------------------------------------------------------------------
// Kernel A: fused precompute, 304 blocks.
//   bx 0..15   : Wv[c][d] = Wk_w[d][c]   (transpose of left half; bx0 also zeros cnt)
//   bx 16..271 : Tb[k][d] = Wk_b[d] + sum_e Wk_w[d][256+e]*embK[k][e], 2 keys/block
//   bx 272..303: Qp[b][*] = dpfp(Wq_w @ embK[q[b]] + Wq_b)
// ---------------------------------------------------------------------------
__global__ __launch_bounds__(256) void k_pre(const int* __restrict__ q,
                                             const float* __restrict__ embK,
                                             const float* __restrict__ Wk_w,
                                             const float* __restrict__ Wk_b,
                                             const float* __restrict__ Wq_w,
                                             const float* __restrict__ Wq_b,
                                             float* __restrict__ Wv,
                                             float* __restrict__ Tb,
                                             float* __restrict__ Qp,
                                             int* __restrict__ cnt) {
  __shared__ float smem[64 * 65];
  int bx = blockIdx.x, tid = threadIdx.x;

  if (bx == 0 && tid < BSZ) cnt[tid] = 0;  // completion counters for k_main

  if (bx < 16) {
    // ---- transpose left 256 cols of Wk_w into Wv (64x64 tiles) ----
    float (*tile)[65] = (float(*)[65])smem;
    int c0 = (bx & 3) * 64, d0 = (bx >> 2) * 64;
    int tx = tid & 63, ty = tid >> 6;
#pragma unroll
    for (int j = 0; j < 16; ++j) {
      int dd = ty + j * 4;
      tile[dd][tx] = Wk_w[(d0 + dd) * 512 + c0 + tx];
    }
    __syncthreads();
#pragma unroll
    for (int j = 0; j < 16; ++j) {
      int cc = ty + j * 4;
      Wv[(c0 + cc) * 256 + d0 + tx] = tile[tx][cc];
    }
  } else if (bx < 272) {
    // ---- Tb build: 2 keys per block; emb rows are wave-uniform reads ----
    int k0 = (bx - 16) * 2;
    const float* e0p = embK + k0 * 256;
    const float* e1p = e0p + 256;
    const float* wr = Wk_w + tid * 512 + 256;  // thread tid = output dim d
    float acc0 = 0.f, acc1 = 0.f;
    for (int e4 = 0; e4 < 64; ++e4) {
      float4 wv = *(const float4*)(wr + e4 * 4);
      float4 a = *(const float4*)(e0p + e4 * 4);
      float4 c = *(const float4*)(e1p + e4 * 4);
      acc0 += wv.x * a.x + wv.y * a.y + wv.z * a.z + wv.w * a.w;
      acc1 += wv.x * c.x + wv.y * c.y + wv.z * c.z + wv.w * c.w;
    }
    float bias = Wk_b[tid];
    Tb[k0 * 256 + tid] = acc0 + bias;
    Tb[(k0 + 1) * 256 + tid] = acc1 + bias;
  } else {
    // ---- Qp build: one query per block; qe row is wave-uniform ----
    int b = bx - 272;
    float* xq = smem;  // 512
    const float* qe = embK + q[b] * 256;
    const float* wr = Wq_w + tid * 256;
    float acc = Wq_b[tid];
    for (int e4 = 0; e4 < 64; ++e4) {
      float4 wv = *(const float4*)(wr + e4 * 4);
      float4 qv = *(const float4*)(qe + e4 * 4);
      acc += wv.x * qv.x + wv.y * qv.y + wv.z * qv.z + wv.w * qv.w;
    }
    xq[tid] = fmaxf(acc, 0.f);
    xq[tid + 256] = fmaxf(-acc, 0.f);
    __syncthreads();
#pragma unroll
    for (int t = 0; t < 4; ++t) {
      int p = tid + t * 256;
      float v = (p < 512) ? xq[p] * xq[(p - 1) & 511]
                          : xq[p - 512] * xq[(p - 514) & 511];
      Qp[b * 1024 + p] = v;
    }
  }
}

// ---------------------------------------------------------------------------
// Kernel B: main scoring + fused final reduction.
// Lane L owns d in [4L,4L+4); both relu halves in registers. Roll neighbors
// via 4 shuffles from lane-1 (lane 0 wraps across halves). Dense per-chunk
// partials numP[b][chunk][v]; the last chunk-block per b (decoupled counter +
// device fences) reduces all 64 chunks, computes den = sum_v, divides, stores.
// ---------------------------------------------------------------------------
__global__ __launch_bounds__(256) void k_main(const int* __restrict__ x,
                                              const float* __restrict__ Wv,
                                              const float* __restrict__ Tb,
                                              const float* __restrict__ Qp,
                                              float* __restrict__ numP,
                                              int* __restrict__ cnt,
                                              float* __restrict__ out) {
  __shared__ float numW[4][256];
  __shared__ float red[256];
  __shared__ int kidx[CHUNK], vidx[CHUNK];
  __shared__ int isLast;
  int tid = threadIdx.x;
  int lane = tid & 63, w = tid >> 6;
  int b = blockIdx.x / NCHUNK, chunk = blockIdx.x % NCHUNK;
  int l0 = chunk * CHUNK;
  const int* xb = x + b * 2 * SLEN;

  if (tid < CHUNK) kidx[tid] = xb[l0 + tid];
  else if (tid < 2 * CHUNK) vidx[tid - CHUNK] = xb[SLEN + l0 + tid - CHUNK];
#pragma unroll
  for (int t = 0; t < 4; ++t) ((float*)numW)[tid + t * 256] = 0.f;
  __syncthreads();

  const float* Qb = Qp + b * 1024 + 4 * lane;
  float4 qa = *(const float4*)(Qb);        // Q[4L+j]      (half0, x_{i-1})
  float4 qc = *(const float4*)(Qb + 256);  // Q[256+4L+j]  (half1, x_{i-1})
  float4 qb4 = *(const float4*)(Qb + 512); // Q[512+4L+j]  (half0, x_{i-2})
  float4 qd = *(const float4*)(Qb + 768);  // Q[768+4L+j]  (half1, x_{i-2})
  const float QA[4] = {qa.x, qa.y, qa.z, qa.w};
  const float QC[4] = {qc.x, qc.y, qc.z, qc.w};
  const float QB[4] = {qb4.x, qb4.y, qb4.z, qb4.w};
  const float QD[4] = {qd.x, qd.y, qd.z, qd.w};

  int src = (lane + 63) & 63;
  bool l0lane = (lane == 0);

  for (int p8 = 0; p8 < CHUNK / 4; ++p8) {
    int l = w + p8 * 4;
    int key = kidx[l];
    int vcol = vidx[l] - NVAL;
    float4 wv = *(const float4*)(Wv + vcol * 256 + 4 * lane);
    float4 tv = *(const float4*)(Tb + key * 256 + 4 * lane);
    float y[4] = {wv.x + tv.x, wv.y + tv.y, wv.z + tv.z, wv.w + tv.w};
    float xp0[4], xp1[4];
#pragma unroll
    for (int j = 0; j < 4; ++j) {
      xp0[j] = fmaxf(y[j], 0.f);
      xp1[j] = fmaxf(-y[j], 0.f);
    }
    float p0_3 = __shfl(xp0[3], src, 64);
    float p0_2 = __shfl(xp0[2], src, 64);
    float p1_3 = __shfl(xp1[3], src, 64);
    float p1_2 = __shfl(xp1[2], src, 64);
    // lane 0 wraps across halves: x_{-1}=x_{511} (xp1 of lane 63), x_{255} (xp0 of lane 63)
    float h0p1 = l0lane ? p1_3 : p0_3;
    float h0p2 = l0lane ? p1_2 : p0_2;
    float h1p1 = l0lane ? p0_3 : p1_3;
    float h1p2 = l0lane ? p0_2 : p1_2;

    float s = xp0[0] * (h0p1 * QA[0] + h0p2 * QB[0])
            + xp0[1] * (xp0[0] * QA[1] + h0p1 * QB[1])
            + xp0[2] * (xp0[1] * QA[2] + xp0[0] * QB[2])
            + xp0[3] * (xp0[2] * QA[3] + xp0[1] * QB[3])
            + xp1[0] * (h1p1 * QC[0] + h1p2 * QD[0])
            + xp1[1] * (xp1[0] * QC[1] + h1p1 * QD[1])
            + xp1[2] * (xp1[1] * QC[2] + xp1[0] * QD[2])
            + xp1[3] * (xp1[2] * QC[3] + xp1[1] * QD[3]);
#pragma unroll
    for (int off = 32; off >= 1; off >>= 1) s += __shfl_xor(s, off, 64);
    if (lane == 0) numW[w][vcol] += s;
  }
  __syncthreads();
  float tsum = numW[0][tid] + numW[1][tid] + numW[2][tid] + numW[3][tid];
  numP[(b * NCHUNK + chunk) * 256 + tid] = tsum;

  // ---- decoupled completion: last chunk-block for this b reduces ----
  __threadfence();  // release: make numP slice visible device-wide
  if (tid == 0) {
    int old = atomicAdd(&cnt[b], 1);
    isLast = (old == NCHUNK - 1);
  }
  __syncthreads();
  if (!isLast) return;
  __threadfence();  // acquire: see all other blocks' numP slices

  float acc = 0.f;
  const float* p = numP + b * NCHUNK * 256 + tid;
  for (int c = 0; c < NCHUNK; ++c) acc += p[c * 256];
  red[tid] = acc;
  __syncthreads();
  if (tid < 128) red[tid] += red[tid + 128];
  __syncthreads();
  if (tid < 64) {
    float r = red[tid] + red[tid + 64];
#pragma unroll
    for (int off = 32; off >= 1; off >>= 1) r += __shfl_xor(r, off, 64);
    if (tid == 0) red[0] = r;
  }
  __syncthreads();
  out[b * 256 + tid] = acc / (red[0] + 1e-6f);
}

extern "C" void kernel_launch(void* const* d_in, const int* in_sizes, int n_in,
                              void* d_out, int out_size, void* d_ws, size_t ws_size,
                              hipStream_t stream) {
  const int* x = (const int*)d_in[0];
  const int* q = (const int*)d_in[1];
  const float* embK = (const float*)d_in[2];
  const float* Wk_w = (const float*)d_in[3];
  const float* Wk_b = (const float*)d_in[4];
  const float* Wq_w = (const float*)d_in[5];
  const float* Wq_b = (const float*)d_in[6];
  float* out = (float*)d_out;

  char* ws = (char*)d_ws;
  float* Wv   = (float*)ws; ws += 256 * 256 * 4;         // transposed left half of Wk_w
  float* Tb   = (float*)ws; ws += 512 * 256 * 4;         // key table (+bias)
  float* Qp   = (float*)ws; ws += 32 * 1024 * 4;         // dpfp'd queries
  float* numP = (float*)ws; ws += 32 * NCHUNK * 256 * 4; // per-chunk partials
  int*   cnt  = (int*)ws;   ws += 32 * 4;                // per-batch completion counters

  dim3 blk(256);
  k_pre<<<304, blk, 0, stream>>>(q, embK, Wk_w, Wk_b, Wq_w, Wq_b, Wv, Tb, Qp, cnt);
  k_main<<<BSZ * NCHUNK, blk, 0, stream>>>(x, Wv, Tb, Qp, numP, cnt, out);
}

// Round 7
// 96.833 us; speedup vs baseline: 2.4827x; 2.4827x over previous
//
#include <hip/hip_runtime.h>

#define BSZ 32
#define SLEN 2048
#define NVAL 256
#define CHUNK 32                 // positions per k_main block
#define NCHUNK (SLEN / CHUNK)    // 64

// ---------------------------------------------------------------------------
// Kernel A: fused precompute, 304 blocks (LDS-free Tb/Qp branches).
//   bx 0..15   : Wv[c][d] = Wk_w[d][c]   (transpose of left half)
//   bx 16..271 : Tb[k][d] = Wk_b[d] + sum_e Wk_w[d][256+e]*embK[k][e], 2 keys/block
//   bx 272..303: Qp[b][*] = dpfp(Wq_w @ embK[q[b]] + Wq_b)
// ---------------------------------------------------------------------------
__global__ __launch_bounds__(256) void k_pre(const int* __restrict__ q,
                                             const float* __restrict__ embK,
                                             const float* __restrict__ Wk_w,
                                             const float* __restrict__ Wk_b,
                                             const float* __restrict__ Wq_w,
                                             const float* __restrict__ Wq_b,
                                             float* __restrict__ Wv,
                                             float* __restrict__ Tb,
                                             float* __restrict__ Qp) {
  __shared__ float smem[64 * 65];
  int bx = blockIdx.x, tid = threadIdx.x;

  if (bx < 16) {
    // ---- transpose left 256 cols of Wk_w into Wv (64x64 tiles) ----
    float (*tile)[65] = (float(*)[65])smem;
    int c0 = (bx & 3) * 64, d0 = (bx >> 2) * 64;
    int tx = tid & 63, ty = tid >> 6;
#pragma unroll
    for (int j = 0; j < 16; ++j) {
      int dd = ty + j * 4;
      tile[dd][tx] = Wk_w[(d0 + dd) * 512 + c0 + tx];
    }
    __syncthreads();
#pragma unroll
    for (int j = 0; j < 16; ++j) {
      int cc = ty + j * 4;
      Wv[(c0 + cc) * 256 + d0 + tx] = tile[tx][cc];
    }
  } else if (bx < 272) {
    // ---- Tb build: 2 keys per block; emb rows are wave-uniform vector reads ----
    int k0 = (bx - 16) * 2;
    const float* e0p = embK + k0 * 256;
    const float* e1p = e0p + 256;
    const float* wr = Wk_w + tid * 512 + 256;  // thread tid = output dim d
    float acc0 = 0.f, acc1 = 0.f;
    for (int e4 = 0; e4 < 64; ++e4) {
      float4 wv = *(const float4*)(wr + e4 * 4);
      float4 a = *(const float4*)(e0p + e4 * 4);
      float4 c = *(const float4*)(e1p + e4 * 4);
      acc0 += wv.x * a.x + wv.y * a.y + wv.z * a.z + wv.w * a.w;
      acc1 += wv.x * c.x + wv.y * c.y + wv.z * c.z + wv.w * c.w;
    }
    float bias = Wk_b[tid];
    Tb[k0 * 256 + tid] = acc0 + bias;
    Tb[(k0 + 1) * 256 + tid] = acc1 + bias;
  } else {
    // ---- Qp build: one query per block; qe row is wave-uniform ----
    int b = bx - 272;
    float* xq = smem;  // 512
    const float* qe = embK + q[b] * 256;
    const float* wr = Wq_w + tid * 256;
    float acc = Wq_b[tid];
    for (int e4 = 0; e4 < 64; ++e4) {
      float4 wv = *(const float4*)(wr + e4 * 4);
      float4 qv = *(const float4*)(qe + e4 * 4);
      acc += wv.x * qv.x + wv.y * qv.y + wv.z * qv.z + wv.w * qv.w;
    }
    xq[tid] = fmaxf(acc, 0.f);
    xq[tid + 256] = fmaxf(-acc, 0.f);
    __syncthreads();
#pragma unroll
    for (int t = 0; t < 4; ++t) {
      int p = tid + t * 256;
      float v = (p < 512) ? xq[p] * xq[(p - 1) & 511]
                          : xq[p - 512] * xq[(p - 514) & 511];
      Qp[b * 1024 + p] = v;
    }
  }
}

// ---------------------------------------------------------------------------
// Kernel B: main scoring (R5-proven, fence-free). Lane L owns d in [4L,4L+4);
// both relu halves in registers. Roll neighbors via 4 shuffles from lane-1
// (lane 0 wraps across halves). Dense per-chunk partials, no atomics.
// ---------------------------------------------------------------------------
__global__ __launch_bounds__(256) void k_main(const int* __restrict__ x,
                                              const float* __restrict__ Wv,
                                              const float* __restrict__ Tb,
                                              const float* __restrict__ Qp,
                                              float* __restrict__ numP) {
  __shared__ float numW[4][256];
  __shared__ int kidx[CHUNK], vidx[CHUNK];
  int tid = threadIdx.x;
  int lane = tid & 63, w = tid >> 6;
  int b = blockIdx.x / NCHUNK, chunk = blockIdx.x % NCHUNK;
  int l0 = chunk * CHUNK;
  const int* xb = x + b * 2 * SLEN;

  if (tid < CHUNK) kidx[tid] = xb[l0 + tid];
  else if (tid < 2 * CHUNK) vidx[tid - CHUNK] = xb[SLEN + l0 + tid - CHUNK];
#pragma unroll
  for (int t = 0; t < 4; ++t) ((float*)numW)[tid + t * 256] = 0.f;
  __syncthreads();

  const float* Qb = Qp + b * 1024 + 4 * lane;
  float4 qa = *(const float4*)(Qb);        // Q[4L+j]      (half0, x_{i-1})
  float4 qc = *(const float4*)(Qb + 256);  // Q[256+4L+j]  (half1, x_{i-1})
  float4 qb4 = *(const float4*)(Qb + 512); // Q[512+4L+j]  (half0, x_{i-2})
  float4 qd = *(const float4*)(Qb + 768);  // Q[768+4L+j]  (half1, x_{i-2})
  const float QA[4] = {qa.x, qa.y, qa.z, qa.w};
  const float QC[4] = {qc.x, qc.y, qc.z, qc.w};
  const float QB[4] = {qb4.x, qb4.y, qb4.z, qb4.w};
  const float QD[4] = {qd.x, qd.y, qd.z, qd.w};

  int src = (lane + 63) & 63;
  bool l0lane = (lane == 0);

  for (int p8 = 0; p8 < CHUNK / 4; ++p8) {
    int l = w + p8 * 4;
    int key = kidx[l];
    int vcol = vidx[l] - NVAL;
    float4 wv = *(const float4*)(Wv + vcol * 256 + 4 * lane);
    float4 tv = *(const float4*)(Tb + key * 256 + 4 * lane);
    float y[4] = {wv.x + tv.x, wv.y + tv.y, wv.z + tv.z, wv.w + tv.w};
    float xp0[4], xp1[4];
#pragma unroll
    for (int j = 0; j < 4; ++j) {
      xp0[j] = fmaxf(y[j], 0.f);
      xp1[j] = fmaxf(-y[j], 0.f);
    }
    float p0_3 = __shfl(xp0[3], src, 64);
    float p0_2 = __shfl(xp0[2], src, 64);
    float p1_3 = __shfl(xp1[3], src, 64);
    float p1_2 = __shfl(xp1[2], src, 64);
    // lane 0 wraps across halves: x_{-1}=x_{511} (xp1 of lane 63), x_{255} (xp0 of lane 63)
    float h0p1 = l0lane ? p1_3 : p0_3;
    float h0p2 = l0lane ? p1_2 : p0_2;
    float h1p1 = l0lane ? p0_3 : p1_3;
    float h1p2 = l0lane ? p0_2 : p1_2;

    float s = xp0[0] * (h0p1 * QA[0] + h0p2 * QB[0])
            + xp0[1] * (xp0[0] * QA[1] + h0p1 * QB[1])
            + xp0[2] * (xp0[1] * QA[2] + xp0[0] * QB[2])
            + xp0[3] * (xp0[2] * QA[3] + xp0[1] * QB[3])
            + xp1[0] * (h1p1 * QC[0] + h1p2 * QD[0])
            + xp1[1] * (xp1[0] * QC[1] + h1p1 * QD[1])
            + xp1[2] * (xp1[1] * QC[2] + xp1[0] * QD[2])
            + xp1[3] * (xp1[2] * QC[3] + xp1[1] * QD[3]);
#pragma unroll
    for (int off = 32; off >= 1; off >>= 1) s += __shfl_xor(s, off, 64);
    if (lane == 0) numW[w][vcol] += s;
  }
  __syncthreads();
  float tsum = numW[0][tid] + numW[1][tid] + numW[2][tid] + numW[3][tid];
  numP[(b * NCHUNK + chunk) * 256 + tid] = tsum;
}

// ---------------------------------------------------------------------------
// Kernel C: reduce partials over chunks; den[b] = sum_v num[b][v]; divide.
// ---------------------------------------------------------------------------
__global__ __launch_bounds__(256) void k_final(const float* __restrict__ numP,
                                               float* __restrict__ out) {
  __shared__ float red[256];
  int b = blockIdx.x, v = threadIdx.x;
  float acc = 0.f;
  const float* p = numP + b * NCHUNK * 256 + v;
  for (int c = 0; c < NCHUNK; ++c) acc += p[c * 256];
  red[v] = acc;
  __syncthreads();
  if (v < 128) red[v] += red[v + 128];
  __syncthreads();
  if (v < 64) {
    float r = red[v] + red[v + 64];
#pragma unroll
    for (int off = 32; off >= 1; off >>= 1) r += __shfl_xor(r, off, 64);
    if (v == 0) red[0] = r;
  }
  __syncthreads();
  out[b * 256 + v] = acc / (red[0] + 1e-6f);
}

extern "C" void kernel_launch(void* const* d_in, const int* in_sizes, int n_in,
                              void* d_out, int out_size, void* d_ws, size_t ws_size,
                              hipStream_t stream) {
  const int* x = (const int*)d_in[0];
  const int* q = (const int*)d_in[1];
  const float* embK = (const float*)d_in[2];
  const float* Wk_w = (const float*)d_in[3];
  const float* Wk_b = (const float*)d_in[4];
  const float* Wq_w = (const float*)d_in[5];
  const float* Wq_b = (const float*)d_in[6];
  float* out = (float*)d_out;

  char* ws = (char*)d_ws;
  float* Wv   = (float*)ws; ws += 256 * 256 * 4;         // transposed left half of Wk_w
  float* Tb   = (float*)ws; ws += 512 * 256 * 4;         // key table (+bias)
  float* Qp   = (float*)ws; ws += 32 * 1024 * 4;         // dpfp'd queries
  float* numP = (float*)ws; ws += 32 * NCHUNK * 256 * 4; // per-chunk partials

  dim3 blk(256);
  k_pre<<<304, blk, 0, stream>>>(q, embK, Wk_w, Wk_b, Wq_w, Wq_b, Wv, Tb, Qp);
  k_main<<<BSZ * NCHUNK, blk, 0, stream>>>(x, Wv, Tb, Qp, numP);
  k_final<<<BSZ, blk, 0, stream>>>(numP, out);
}

// Round 10
// 92.861 us; speedup vs baseline: 2.5889x; 1.0428x over previous
//
#include <hip/hip_runtime.h>

#define BSZ 32
#define SLEN 2048
#define NVAL 256
#define CHUNK 32                 // positions per k_main block
#define NCHUNK (SLEN / CHUNK)    // 64

// ---------------------------------------------------------------------------
// Kernel A: fused precompute (R5-measured-best variant).
//   blocks 0..15  : Wv[c][d] = Wk_w[d][c]          (transpose of left half)
//   blocks 16..79 : Tb[k][d] = Wk_b[d] + sum_e Wk_w[d][256+e]*embK[k][e]
//   blocks 80..111: Qp[b][*] = dpfp(Wq_w @ embK[q[b]] + Wq_b)
// ---------------------------------------------------------------------------
__global__ __launch_bounds__(256) void k_pre(const int* __restrict__ q,
                                             const float* __restrict__ embK,
                                             const float* __restrict__ Wk_w,
                                             const float* __restrict__ Wk_b,
                                             const float* __restrict__ Wq_w,
                                             const float* __restrict__ Wq_b,
                                             float* __restrict__ Wv,
                                             float* __restrict__ Tb,
                                             float* __restrict__ Qp) {
  __shared__ float smem[64 * 65];
  int bx = blockIdx.x, tid = threadIdx.x;

  if (bx < 16) {
    // ---- transpose left 256 cols of Wk_w into Wv (64x64 tiles) ----
    float (*tile)[65] = (float(*)[65])smem;
    int c0 = (bx & 3) * 64, d0 = (bx >> 2) * 64;
    int tx = tid & 63, ty = tid >> 6;
#pragma unroll
    for (int j = 0; j < 16; ++j) {
      int dd = ty + j * 4;
      tile[dd][tx] = Wk_w[(d0 + dd) * 512 + c0 + tx];
    }
    __syncthreads();
#pragma unroll
    for (int j = 0; j < 16; ++j) {
      int cc = ty + j * 4;
      Wv[(c0 + cc) * 256 + d0 + tx] = tile[tx][cc];
    }
  } else if (bx < 80) {
    // ---- Tb build: 8 keys per block, LDS-broadcast emb ----
    int k0 = (bx - 16) * 8;
    float* emb = smem;  // 8*256
#pragma unroll
    for (int t = 0; t < 8; ++t) emb[t * 256 + tid] = embK[(k0 + t) * 256 + tid];
    __syncthreads();
    float acc[8] = {0.f, 0.f, 0.f, 0.f, 0.f, 0.f, 0.f, 0.f};
    const float* wr = Wk_w + tid * 512 + 256;  // thread tid = output dim d
    for (int e4 = 0; e4 < 64; ++e4) {
      float4 wv = *(const float4*)(wr + e4 * 4);
      const float wvf[4] = {wv.x, wv.y, wv.z, wv.w};
#pragma unroll
      for (int jj = 0; jj < 4; ++jj) {
        float we = wvf[jj];
        int e = e4 * 4 + jj;
#pragma unroll
        for (int k = 0; k < 8; ++k) acc[k] += we * emb[k * 256 + e];
      }
    }
    float bias = Wk_b[tid];
#pragma unroll
    for (int k = 0; k < 8; ++k) Tb[(k0 + k) * 256 + tid] = acc[k] + bias;
  } else {
    // ---- Qp build: one query per block ----
    int b = bx - 80;
    float* qe = smem;        // 256
    float* xq = smem + 256;  // 512
    qe[tid] = embK[q[b] * 256 + tid];
    __syncthreads();
    float acc = Wq_b[tid];
    const float* wr = Wq_w + tid * 256;
    for (int e4 = 0; e4 < 64; ++e4) {
      float4 wv = *(const float4*)(wr + e4 * 4);
      int e = e4 * 4;
      acc += wv.x * qe[e] + wv.y * qe[e + 1] + wv.z * qe[e + 2] + wv.w * qe[e + 3];
    }
    xq[tid] = fmaxf(acc, 0.f);
    xq[tid + 256] = fmaxf(-acc, 0.f);
    __syncthreads();
#pragma unroll
    for (int t = 0; t < 4; ++t) {
      int p = tid + t * 256;
      float v = (p < 512) ? xq[p] * xq[(p - 1) & 511]
                          : xq[p - 512] * xq[(p - 514) & 511];
      Qp[b * 1024 + p] = v;
    }
  }
}

// ---------------------------------------------------------------------------
// Kernel B: main scoring. Lane L owns d in [4L,4L+4); both relu halves in
// registers. Roll neighbors via 4 shuffles from lane-1 (lane 0 wraps across
// halves). Dense per-chunk partials numP[b][chunk][v], no atomics, no fences
// (R6 lesson: device-scope fences x 2048 blocks cost ~165 us on 8 XCDs).
// ---------------------------------------------------------------------------
__global__ __launch_bounds__(256) void k_main(const int* __restrict__ x,
                                              const float* __restrict__ Wv,
                                              const float* __restrict__ Tb,
                                              const float* __restrict__ Qp,
                                              float* __restrict__ numP) {
  __shared__ float numW[4][256];
  __shared__ int kidx[CHUNK], vidx[CHUNK];
  int tid = threadIdx.x;
  int lane = tid & 63, w = tid >> 6;
  int b = blockIdx.x / NCHUNK, chunk = blockIdx.x % NCHUNK;
  int l0 = chunk * CHUNK;
  const int* xb = x + b * 2 * SLEN;

  if (tid < CHUNK) kidx[tid] = xb[l0 + tid];
  else if (tid < 2 * CHUNK) vidx[tid - CHUNK] = xb[SLEN + l0 + tid - CHUNK];
#pragma unroll
  for (int t = 0; t < 4; ++t) ((float*)numW)[tid + t * 256] = 0.f;
  __syncthreads();

  const float* Qb = Qp + b * 1024 + 4 * lane;
  float4 qa = *(const float4*)(Qb);        // Q[4L+j]      (half0, x_{i-1})
  float4 qc = *(const float4*)(Qb + 256);  // Q[256+4L+j]  (half1, x_{i-1})
  float4 qb4 = *(const float4*)(Qb + 512); // Q[512+4L+j]  (half0, x_{i-2})
  float4 qd = *(const float4*)(Qb + 768);  // Q[768+4L+j]  (half1, x_{i-2})
  const float QA[4] = {qa.x, qa.y, qa.z, qa.w};
  const float QC[4] = {qc.x, qc.y, qc.z, qc.w};
  const float QB[4] = {qb4.x, qb4.y, qb4.z, qb4.w};
  const float QD[4] = {qd.x, qd.y, qd.z, qd.w};

  int src = (lane + 63) & 63;
  bool l0lane = (lane == 0);

  for (int p8 = 0; p8 < CHUNK / 4; ++p8) {
    int l = w + p8 * 4;
    int key = kidx[l];
    int vcol = vidx[l] - NVAL;
    float4 wv = *(const float4*)(Wv + vcol * 256 + 4 * lane);
    float4 tv = *(const float4*)(Tb + key * 256 + 4 * lane);
    float y[4] = {wv.x + tv.x, wv.y + tv.y, wv.z + tv.z, wv.w + tv.w};
    float xp0[4], xp1[4];
#pragma unroll
    for (int j = 0; j < 4; ++j) {
      xp0[j] = fmaxf(y[j], 0.f);
      xp1[j] = fmaxf(-y[j], 0.f);
    }
    float p0_3 = __shfl(xp0[3], src, 64);
    float p0_2 = __shfl(xp0[2], src, 64);
    float p1_3 = __shfl(xp1[3], src, 64);
    float p1_2 = __shfl(xp1[2], src, 64);
    // lane 0 wraps across halves: x_{-1}=x_{511} (xp1 of lane 63), x_{255} (xp0 of lane 63)
    float h0p1 = l0lane ? p1_3 : p0_3;
    float h0p2 = l0lane ? p1_2 : p0_2;
    float h1p1 = l0lane ? p0_3 : p1_3;
    float h1p2 = l0lane ? p0_2 : p1_2;

    float s = xp0[0] * (h0p1 * QA[0] + h0p2 * QB[0])
            + xp0[1] * (xp0[0] * QA[1] + h0p1 * QB[1])
            + xp0[2] * (xp0[1] * QA[2] + xp0[0] * QB[2])
            + xp0[3] * (xp0[2] * QA[3] + xp0[1] * QB[3])
            + xp1[0] * (h1p1 * QC[0] + h1p2 * QD[0])
            + xp1[1] * (xp1[0] * QC[1] + h1p1 * QD[1])
            + xp1[2] * (xp1[1] * QC[2] + xp1[0] * QD[2])
            + xp1[3] * (xp1[2] * QC[3] + xp1[1] * QD[3]);
#pragma unroll
    for (int off = 32; off >= 1; off >>= 1) s += __shfl_xor(s, off, 64);
    if (lane == 0) numW[w][vcol] += s;
  }
  __syncthreads();
  float tsum = numW[0][tid] + numW[1][tid] + numW[2][tid] + numW[3][tid];
  numP[(b * NCHUNK + chunk) * 256 + tid] = tsum;
}

// ---------------------------------------------------------------------------
// Kernel C: reduce partials over chunks; den[b] = sum_v num[b][v]; divide.
// ---------------------------------------------------------------------------
__global__ __launch_bounds__(256) void k_final(const float* __restrict__ numP,
                                               float* __restrict__ out) {
  __shared__ float red[256];
  int b = blockIdx.x, v = threadIdx.x;
  float acc = 0.f;
  const float* p = numP + b * NCHUNK * 256 + v;
  for (int c = 0; c < NCHUNK; ++c) acc += p[c * 256];
  red[v] = acc;
  __syncthreads();
  if (v < 128) red[v] += red[v + 128];
  __syncthreads();
  if (v < 64) {
    float r = red[v] + red[v + 64];
#pragma unroll
    for (int off = 32; off >= 1; off >>= 1) r += __shfl_xor(r, off, 64);
    if (v == 0) red[0] = r;
  }
  __syncthreads();
  out[b * 256 + v] = acc / (red[0] + 1e-6f);
}

extern "C" void kernel_launch(void* const* d_in, const int* in_sizes, int n_in,
                              void* d_out, int out_size, void* d_ws, size_t ws_size,
                              hipStream_t stream) {
  const int* x = (const int*)d_in[0];
  const int* q = (const int*)d_in[1];
  const float* embK = (const float*)d_in[2];
  const float* Wk_w = (const float*)d_in[3];
  const float* Wk_b = (const float*)d_in[4];
  const float* Wq_w = (const float*)d_in[5];
  const float* Wq_b = (const float*)d_in[6];
  float* out = (float*)d_out;

  char* ws = (char*)d_ws;
  float* Wv   = (float*)ws; ws += 256 * 256 * 4;         // transposed left half of Wk_w
  float* Tb   = (float*)ws; ws += 512 * 256 * 4;         // key table (+bias)
  float* Qp   = (float*)ws; ws += 32 * 1024 * 4;         // dpfp'd queries
  float* numP = (float*)ws; ws += 32 * NCHUNK * 256 * 4; // per-chunk partials

  dim3 blk(256);
  k_pre<<<112, blk, 0, stream>>>(q, embK, Wk_w, Wk_b, Wq_w, Wq_b, Wv, Tb, Qp);
  k_main<<<BSZ * NCHUNK, blk, 0, stream>>>(x, Wv, Tb, Qp, numP);
  k_final<<<BSZ, blk, 0, stream>>>(numP, out);
}